// Round 10
// baseline (51.343 us; speedup 1.0000x reference)
//
#include <hip/hip_runtime.h>

// Problem constants (from reference setup_inputs): B=4, N=4096, D=128.
constexpr int BATCH = 4;
constexpr int N = 4096;
constexpr int D = 128;
constexpr int J4 = N / 4;                      // 1024 float4s per output row
constexpr size_t TOTAL4 = (size_t)BATCH * N * J4;  // 16,777,216 float4s

typedef float vfloat4 __attribute__((ext_vector_type(4)));

__device__ __forceinline__ float dot4(const vfloat4 a, const vfloat4 b) {
    return a.x * b.x + a.y * b.y + a.z * b.z + a.w * b.w;
}

// ---------------------------------------------------------------------------
// Kernel 1: per-row dual dot products (v3, unchanged since R6).
// Wave handles 4 rows via 16-lane groups; two coalesced float4 loads/lane;
// 4-step butterfly reduce within 16 lanes.
// ---------------------------------------------------------------------------
__global__ __launch_bounds__(256)
void dots_kernel(const float* __restrict__ E,
                 const float* __restrict__ W,
                 float* __restrict__ A,
                 float* __restrict__ Bv) {
    const int gtid = blockIdx.x * blockDim.x + threadIdx.x;
    const int wave = gtid >> 6;          // 0..4095
    const int g    = (threadIdx.x >> 4) & 3;
    const int s    = threadIdx.x & 15;
    const int row  = wave * 4 + g;       // exact fit: 4096*4 = 16384 rows

    const float* rp = E + (size_t)row * D;
    const vfloat4 e1  = *reinterpret_cast<const vfloat4*>(rp + s * 4);
    const vfloat4 e2  = *reinterpret_cast<const vfloat4*>(rp + 64 + s * 4);
    const vfloat4 wi1 = *reinterpret_cast<const vfloat4*>(W + s * 4);
    const vfloat4 wi2 = *reinterpret_cast<const vfloat4*>(W + 64 + s * 4);
    const vfloat4 wj1 = *reinterpret_cast<const vfloat4*>(W + D + s * 4);
    const vfloat4 wj2 = *reinterpret_cast<const vfloat4*>(W + D + 64 + s * 4);

    float pa = dot4(e1, wi1) + dot4(e2, wi2);
    float pb = dot4(e1, wj1) + dot4(e2, wj2);

    #pragma unroll
    for (int off = 8; off >= 1; off >>= 1) {
        pa += __shfl_xor(pa, off);
        pb += __shfl_xor(pb, off);
    }
    if (s == 0) {
        A[row]  = pa;
        Bv[row] = pb;
    }
}

// ---------------------------------------------------------------------------
// Kernel 2: outer-sum, FLAT GLOBAL SWEEP (A/B vs R6 block-tiled):
//   out[idx] = A[idx>>10] + Bv4[(idx>>22)<<10 | (idx&1023)]
// Grid-stride with stride = 2048*256 = 2^19 float4s: per iteration the WHOLE
// GRID writes one contiguous 8 MB chunk then advances — exactly the rocclr
// fill pattern that reaches 7.0-7.15 TB/s. Per iteration per wave:
//   row is wave-uniform (64 float4 = 1KB, row = 16KB) -> 1 scalar A load,
//   b4 = 1KB/wave sequential from 16KB L1-resident Bv slice, 1 plain store.
// Plain stores (R4 A/B: NT costs ~9 us on gfx950).
// ---------------------------------------------------------------------------
__global__ __launch_bounds__(256)
void outer_kernel(const float* __restrict__ A,
                  const float* __restrict__ Bv,
                  vfloat4* __restrict__ out) {
    const vfloat4* __restrict__ bv4 = reinterpret_cast<const vfloat4*>(Bv);
    const size_t stride = (size_t)gridDim.x * blockDim.x;   // 524288

    for (size_t idx = (size_t)blockIdx.x * blockDim.x + threadIdx.x;
         idx < TOTAL4; idx += stride) {
        const int j4    = (int)(idx & (J4 - 1));
        const int row   = (int)(idx >> 10);
        const int batch = row >> 12;
        const float a   = A[row];                       // wave-uniform
        const vfloat4 b4 = bv4[(batch << 10) | j4];     // L1-resident
        out[idx] = b4 + a;
    }
}

extern "C" void kernel_launch(void* const* d_in, const int* in_sizes, int n_in,
                              void* d_out, int out_size, void* d_ws, size_t ws_size,
                              hipStream_t stream) {
    const float* E = (const float*)d_in[0];   // (4, 4096, 128) f32
    const float* W = (const float*)d_in[1];   // (1, 256) f32

    // workspace: A (16384 f32) then Bv (16384 f32) = 128 KB
    float* A  = (float*)d_ws;
    float* Bv = A + (size_t)BATCH * N;

    // Kernel 1: 16384 rows, 4 rows/wave, 16 rows/block -> 1024 blocks
    dots_kernel<<<(BATCH * N) / 16, 256, 0, stream>>>(E, W, A, Bv);

    // Kernel 2: flat sweep, 2048 blocks x 256, 32 iterations/thread
    outer_kernel<<<2048, 256, 0, stream>>>(A, Bv, (vfloat4*)d_out);
}